// Round 3
// baseline (370.411 us; speedup 1.0000x reference)
//
#include <hip/hip_runtime.h>
#include <stdint.h>

// m_btabl — round 6: two-kernel split (stream Z to global, then GEMM+tail).
//
// r5 post-mortem: btabl ~113 us vs ~20 us model. Monolithic block shape
// (100 KB stream -> barrier -> MFMA -> barrier -> tail) never reaches its
// occupancy (r3 counters: 14.4% ~= 1 block/CU effective vs 3-block LDS
// capacity); the barrier convoy keeps choking the stream phase.
//
// r6: decouple regimes. The harness's own 800 MiB poison fill runs at 85%
// of HBM peak -> a dumb barrier-free streaming kernel is the proven-fast
// shape on this machine.
//   zgemm:      thread = one 80 B row-pair of one sample; 5x float4 -> reg,
//               100 FMA (W2 uniform s_load), bf16 pack, 5 contiguous u32
//               stores of Z[group][col 0..319][k 0..39] packed bf16.
//               No LDS, no barriers, 10240 blocks x 256 thr.
//   btabl_gemm: per 64-sample group: coalesced 25.6 KB Z->LDS copy at MFMA
//               stride 48 (aug slot skipped; one-hot synthesized), then the
//               proven stage-2 MFMA + X3 epilogue + stage-3 tail verbatim.
// Z lives in d_ws at +16 KB (52.4 MB; ws is ~800 MiB — the poison fill's
// WRITE_SIZE). If ws_size is too small we fall back to the r5 monolithic
// kernel (kept below) — correctness never depends on the ws assumption.
//
// ws layout (floats) from prep_kernel (unchanged):
//   [0,3096)     W1 image, bf16 ushort[129*48] (bias folded at k=40..44, row128=0)
//   [3096,3608)  w1b pack f32 [128][4]
//   [3608,3644)  consts: Wm(25, diag 0.2) | W2b(5) | TB(3) | lam | pad
//   [3644,3694)  W2s (50)
//   [4096,...)   Z bf16 [ngroups][320][40]   (zgemm -> btabl_gemm)

typedef short bf16x8 __attribute__((ext_vector_type(8)));
typedef float f32x4v __attribute__((ext_vector_type(4)));

#define NTP 256
#define NTM 320

__device__ __forceinline__ unsigned short f2bf(float f) {
    unsigned int u = __float_as_uint(f);
    u += 0x7FFFu + ((u >> 16) & 1u);   // round-to-nearest-even
    return (unsigned short)(u >> 16);
}

// ---------------- prep kernel (unchanged) ----------------
__device__ __forceinline__ float block_reduce_sum(float v, float* red, int tid) {
    #pragma unroll
    for (int off = 32; off > 0; off >>= 1) v += __shfl_xor(v, off, 64);
    if ((tid & 63) == 0) red[tid >> 6] = v;
    __syncthreads();
    float r = red[0] + red[1] + red[2] + red[3];
    __syncthreads();
    return r;
}

__global__ __launch_bounds__(NTP)
void prep_kernel(const float* __restrict__ W1, const float* __restrict__ W2,
                 const float* __restrict__ B,  const float* __restrict__ Tw1,
                 const float* __restrict__ Tw, const float* __restrict__ Tw2,
                 const float* __restrict__ TB, const float* __restrict__ l,
                 float* __restrict__ ws)
{
    __shared__ float red[4];
    const int tid = threadIdx.x;
    float ss;
    ss = 0.f; for (int i = tid; i < 4800; i += NTP) { float w = W1[i];  ss += w*w; }
    const float n1 = sqrtf(block_reduce_sum(ss, red, tid));
    ss = 0.f; for (int i = tid; i < 50;   i += NTP) { float w = W2[i];  ss += w*w; }
    const float n2 = sqrtf(block_reduce_sum(ss, red, tid));
    ss = 0.f; for (int i = tid; i < 360;  i += NTP) { float w = Tw1[i]; ss += w*w; }
    const float n3 = sqrtf(block_reduce_sum(ss, red, tid));
    ss = 0.f; for (int i = tid; i < 25;   i += NTP) { float w = Tw[i];  ss += w*w; }
    const float n4 = sqrtf(block_reduce_sum(ss, red, tid));
    ss = 0.f; for (int i = tid; i < 5;    i += NTP) { float w = Tw2[i]; ss += w*w; }
    const float n5 = sqrtf(block_reduce_sum(ss, red, tid));

    const float s1 = n1 > 10.f ? 10.f/(1e-8f+n1) : 1.f;
    const float s2 = n2 > 10.f ? 10.f/(1e-8f+n2) : 1.f;
    const float s3 = n3 > 10.f ? 10.f/(1e-8f+n3) : 1.f;
    const float s4 = n4 > 10.f ? 10.f/(1e-8f+n4) : 1.f;
    const float s5 = n5 > 10.f ? 10.f/(1e-8f+n5) : 1.f;

    unsigned short* img = (unsigned short*)ws;
    for (int i = tid; i < 129*48; i += NTP) {
        const int e = i / 48, k = i - e*48;
        float v = 0.f;
        if (e < 120) {
            if (k < 40)      v = W1[e*40 + k] * s1;
            else if (k < 45) v = B[e*5 + (k-40)];
        }
        img[i] = f2bf(v);
    }
    for (int i = tid; i < 512; i += NTP) {
        const int e = i >> 2, c = i & 3;
        ws[3096 + i] = (c < 3 && e < 120) ? Tw1[c*120 + e] * s3 : 0.f;
    }
    for (int i = tid; i < 36; i += NTP) {
        float v = 0.f;
        if (i < 25)      { int r = i/5, c = i - r*5; v = (r == c) ? 0.2f : Tw[i]*s4; }
        else if (i < 30) v = Tw2[i-25] * s5;
        else if (i < 33) v = TB[i-30];
        else if (i == 33){ float lv = l[0]; v = fminf(fmaxf(lv, 0.f), 1.f); }
        ws[3608 + i] = v;
    }
    for (int i = tid; i < 50; i += NTP) ws[3644 + i] = W2[i] * s2;
}

// ---------------- zgemm: streaming stage-1 -> Z in global ----------------
// Z[group][col][k]: col = (s%64)*5 + t, k = 0..39, bf16, packed stride 40.
__global__ __launch_bounds__(256)
void zgemm_kernel(const float* __restrict__ x, const float* __restrict__ ws,
                  unsigned short* __restrict__ zg, int nsamp)
{
    const int p = blockIdx.x * 256 + threadIdx.x;
    int s = p / 20;
    const int r20 = p - s * 20;                     // row-pair index
    if (s >= nsamp) s = nsamp - 1;                  // duplicate work, benign
    const float* W2p = ws + 3644;                   // uniform -> s_load

    const float4* xv = (const float4*)(x + (size_t)s*400 + r20*20);
    float xf[20];
    #pragma unroll
    for (int i = 0; i < 5; i++) {
        const float4 q = xv[i];                     // 5x global_load_dwordx4
        xf[i*4+0] = q.x; xf[i*4+1] = q.y; xf[i*4+2] = q.z; xf[i*4+3] = q.w;
    }

    const int g  = s >> 6;
    const int sl = s & 63;
    unsigned short* zc = zg + (size_t)g*12800 + sl*200 + 2*r20;
    #pragma unroll
    for (int t = 0; t < 5; t++) {
        float z0 = 0.f, z1 = 0.f;
        #pragma unroll
        for (int k = 0; k < 10; k++) {
            const float w = W2p[k*5 + t];           // SGPR operand
            z0 = fmaf(xf[k],      w, z0);
            z1 = fmaf(xf[10 + k], w, z1);
        }
        *(unsigned int*)(zc + t*40) =
            (unsigned int)f2bf(z0) | ((unsigned int)f2bf(z1) << 16);
    }
}

// ---------------- btabl_gemm: Z -> MFMA GEMM + attention tail ----------------
__global__ __launch_bounds__(NTM)
void btabl_gemm(const unsigned short* __restrict__ zg, const float* __restrict__ ws,
                float* __restrict__ out, int nsamp)
{
    __align__(16) __shared__ unsigned short sW1[129*48];       // 12384 B
    __align__(16) __shared__ float          sWp[128*4];        // 2048 B
    __align__(16) __shared__ float          sC[36];            // 144 B
    __align__(16) __shared__ unsigned short sZ[320*48 + 16];   // 30752 B (+overflow pad)
    __align__(16) __shared__ float          sX3[320*3];        // 3840 B

    const int tid  = threadIdx.x;
    const int wave = tid >> 6;
    const int lane = tid & 63;

    // ---- stage weights into LDS ----
    {
        const float4* src = (const float4*)ws;
        float4* d1 = (float4*)sW1;
        #pragma unroll
        for (int i = 0; i < 3; i++) {
            const int idx = tid + i*NTM;
            if (idx < 774) d1[idx] = src[idx];
        }
        if (tid < 128) ((float4*)sWp)[tid] = src[774 + tid];
        if (tid < 9)   ((float4*)sC)[tid]  = src[902 + tid];
    }

    // ---- one-hot K-augmentation (k=40..47) for col = tid — Z-independent ----
    {
        bf16x8 oh = {0,0,0,0,0,0,0,0};
        oh[tid % 5] = (short)0x3F80;                           // bf16 1.0 at k=40+col%5
        *(bf16x8*)(sZ + tid*48 + 40) = oh;
    }

    // ---- copy Z image: global packed [320][40] -> LDS stride-48 ----
    // 1600 16B-units; thread t handles unit u=t%5 of cols i*64 + t/5.
    {
        const int u  = tid % 5;
        const int c0 = tid / 5;
        const unsigned short* gsrc = zg + (size_t)blockIdx.x * 12800;
        #pragma unroll
        for (int i = 0; i < 5; i++) {
            const int col = i*64 + c0;
            const float4 v = *(const float4*)(gsrc + (size_t)col*40 + u*8);
            *(float4*)(sZ + col*48 + u*8) = v;     // aug slot (u==5) untouched
        }
    }
    __syncthreads();

    // ---- stage 2: MFMA GEMM + X3 epilogue (unchanged, proven r3-r5) ----
    const int quad = lane >> 4;
    const int m    = lane & 15;
    const int colBase = wave * 64;

    bf16x8 Bf[4][2];
    const bf16x8 z8 = {0,0,0,0,0,0,0,0};
    #pragma unroll
    for (int nt = 0; nt < 4; nt++) {
        const int col = colBase + nt*16 + m;
        Bf[nt][0] = *(const bf16x8*)(sZ + col*48 + quad*8);
        bf16x8 b1 = *(const bf16x8*)(sZ + col*48 + 32 + quad*8);  // quads 2,3 overflow
        Bf[nt][1] = (quad >= 2) ? z8 : b1;                         // k>=48 pad -> 0
    }

    float X3p[4][3];
    #pragma unroll
    for (int nt = 0; nt < 4; nt++)
        #pragma unroll
        for (int j = 0; j < 3; j++) X3p[nt][j] = 0.f;

    const f32x4v zacc = {0.f, 0.f, 0.f, 0.f};
    #pragma unroll
    for (int mt = 0; mt < 8; mt++) {
        const unsigned short* arow = sW1 + (mt*16 + m)*48;
        const bf16x8 A0 = *(const bf16x8*)(arow + quad*8);
        const bf16x8 A1 = *(const bf16x8*)(arow + 32 + quad*8);   // overflow -> row128=0
        f32x4v wp[4];
        #pragma unroll
        for (int r = 0; r < 4; r++)
            wp[r] = *(const f32x4v*)(sWp + (mt*16 + quad*4 + r)*4);
        #pragma unroll
        for (int nt = 0; nt < 4; nt++) {
            f32x4v acc = __builtin_amdgcn_mfma_f32_16x16x32_bf16(A0, Bf[nt][0], zacc, 0, 0, 0);
            acc = __builtin_amdgcn_mfma_f32_16x16x32_bf16(A1, Bf[nt][1], acc, 0, 0, 0);
            #pragma unroll
            for (int r = 0; r < 4; r++) {
                const float h = fmaxf(acc[r], 0.f);               // bias folded in GEMM
                X3p[nt][0] = fmaf(wp[r][0], h, X3p[nt][0]);
                X3p[nt][1] = fmaf(wp[r][1], h, X3p[nt][1]);
                X3p[nt][2] = fmaf(wp[r][2], h, X3p[nt][2]);
            }
        }
    }

    #pragma unroll
    for (int nt = 0; nt < 4; nt++) {
        #pragma unroll
        for (int j = 0; j < 3; j++) {
            float v = X3p[nt][j];
            v += __shfl_xor(v, 16, 64);
            v += __shfl_xor(v, 32, 64);
            X3p[nt][j] = v;
        }
    }
    if (quad == 0) {
        #pragma unroll
        for (int nt = 0; nt < 4; nt++) {
            const int col = colBase + nt*16 + m;
            sX3[col*3 + 0] = X3p[nt][0];
            sX3[col*3 + 1] = X3p[nt][1];
            sX3[col*3 + 2] = X3p[nt][2];
        }
    }
    __syncthreads();

    // ---- stage 3: attention + output softmax, one thread per sample ----
    if (tid < 64) {
        const int sGlob = blockIdx.x * 64 + tid;
        float X3v[3][5];
        #pragma unroll
        for (int t = 0; t < 5; t++)
            #pragma unroll
            for (int j = 0; j < 3; j++)
                X3v[j][t] = sX3[(tid*5 + t)*3 + j];

        const float lam  = sC[33];
        const float olam = 1.f - lam;
        float y[3];
        #pragma unroll
        for (int j = 0; j < 3; j++) {
            float S[5];
            #pragma unroll
            for (int t = 0; t < 5; t++) {
                float a = 0.f;
                #pragma unroll
                for (int k = 0; k < 5; k++)
                    a = fmaf(X3v[j][k], sC[k*5 + t], a);
                S[t] = a;
            }
            float mx = S[0];
            #pragma unroll
            for (int t = 1; t < 5; t++) mx = fmaxf(mx, S[t]);
            float ex[5], se = 0.f;
            #pragma unroll
            for (int t = 0; t < 5; t++) { ex[t] = __expf(S[t] - mx); se += ex[t]; }
            const float inv = 1.f / se;
            float yj = sC[30 + j];
            #pragma unroll
            for (int t = 0; t < 5; t++) {
                const float a  = ex[t] * inv;
                const float xc = X3v[j][t] * (lam + olam * a);
                yj = fmaf(xc, sC[25 + t], yj);
            }
            y[j] = yj;
        }
        const float mx = fmaxf(y[0], fmaxf(y[1], y[2]));
        const float e0 = __expf(y[0]-mx), e1 = __expf(y[1]-mx), e2 = __expf(y[2]-mx);
        const float inv = 1.f / (e0 + e1 + e2);
        if (sGlob < nsamp) {
            float* o = out + (size_t)sGlob*3;
            o[0] = e0*inv; o[1] = e1*inv; o[2] = e2*inv;
        }
    }
}

// ---------------- fallback: r5 monolithic kernel (used if ws too small) ----------------
__global__ __launch_bounds__(NTM, 4)
void btabl_main(const float* __restrict__ x, const float* __restrict__ ws,
                float* __restrict__ out, int nsamp)
{
    __align__(16) __shared__ unsigned short sW1[129*48];
    __align__(16) __shared__ float          sWp[128*4];
    __align__(16) __shared__ float          sC[36];
    __align__(16) __shared__ unsigned short sZ[320*48 + 16];
    __align__(16) __shared__ float          sX3[320*3];

    const int tid  = threadIdx.x;
    const int wave = tid >> 6;
    const int lane = tid & 63;

    {
        const float4* src = (const float4*)ws;
        float4* d1 = (float4*)sW1;
        #pragma unroll
        for (int i = 0; i < 3; i++) {
            const int idx = tid + i*NTM;
            if (idx < 774) d1[idx] = src[idx];
        }
        if (tid < 128) ((float4*)sWp)[tid] = src[774 + tid];
        if (tid < 9)   ((float4*)sC)[tid]  = src[902 + tid];
    }
    {
        bf16x8 oh = {0,0,0,0,0,0,0,0};
        oh[tid % 5] = (short)0x3F80;
        *(bf16x8*)(sZ + tid*48 + 40) = oh;
    }
    __syncthreads();

    {
        const int p   = tid;
        const int s16 = p / 20;
        const int r20 = p - s16*20;
        const float* W2p = ws + 3644;

        #pragma unroll
        for (int r = 0; r < 4; r++) {
            int sG = blockIdx.x*64 + r*16 + s16;
            sG = sG < nsamp ? sG : (nsamp - 1);
            const float4* xv = (const float4*)(x + (size_t)sG*400 + r20*20);
            float xf[20];
            #pragma unroll
            for (int i = 0; i < 5; i++) {
                const float4 q = xv[i];
                xf[i*4+0] = q.x; xf[i*4+1] = q.y; xf[i*4+2] = q.z; xf[i*4+3] = q.w;
            }
            const int col0 = (r*16 + s16)*5;
            #pragma unroll
            for (int t = 0; t < 5; t++) {
                float z0 = 0.f, z1 = 0.f;
                #pragma unroll
                for (int k = 0; k < 10; k++) {
                    const float w = W2p[k*5 + t];
                    z0 = fmaf(xf[k],      w, z0);
                    z1 = fmaf(xf[10 + k], w, z1);
                }
                const unsigned int pk =
                    (unsigned int)f2bf(z0) | ((unsigned int)f2bf(z1) << 16);
                *(unsigned int*)(sZ + (col0 + t)*48 + 2*r20) = pk;
            }
        }
    }
    __syncthreads();

    const int quad = lane >> 4;
    const int m    = lane & 15;
    const int colBase = wave * 64;

    bf16x8 Bf[4][2];
    const bf16x8 z8 = {0,0,0,0,0,0,0,0};
    #pragma unroll
    for (int nt = 0; nt < 4; nt++) {
        const int col = colBase + nt*16 + m;
        Bf[nt][0] = *(const bf16x8*)(sZ + col*48 + quad*8);
        bf16x8 b1 = *(const bf16x8*)(sZ + col*48 + 32 + quad*8);
        Bf[nt][1] = (quad >= 2) ? z8 : b1;
    }

    float X3p[4][3];
    #pragma unroll
    for (int nt = 0; nt < 4; nt++)
        #pragma unroll
        for (int j = 0; j < 3; j++) X3p[nt][j] = 0.f;

    const f32x4v zacc = {0.f, 0.f, 0.f, 0.f};
    #pragma unroll
    for (int mt = 0; mt < 8; mt++) {
        const unsigned short* arow = sW1 + (mt*16 + m)*48;
        const bf16x8 A0 = *(const bf16x8*)(arow + quad*8);
        const bf16x8 A1 = *(const bf16x8*)(arow + 32 + quad*8);
        f32x4v wp[4];
        #pragma unroll
        for (int r = 0; r < 4; r++)
            wp[r] = *(const f32x4v*)(sWp + (mt*16 + quad*4 + r)*4);
        #pragma unroll
        for (int nt = 0; nt < 4; nt++) {
            f32x4v acc = __builtin_amdgcn_mfma_f32_16x16x32_bf16(A0, Bf[nt][0], zacc, 0, 0, 0);
            acc = __builtin_amdgcn_mfma_f32_16x16x32_bf16(A1, Bf[nt][1], acc, 0, 0, 0);
            #pragma unroll
            for (int r = 0; r < 4; r++) {
                const float h = fmaxf(acc[r], 0.f);
                X3p[nt][0] = fmaf(wp[r][0], h, X3p[nt][0]);
                X3p[nt][1] = fmaf(wp[r][1], h, X3p[nt][1]);
                X3p[nt][2] = fmaf(wp[r][2], h, X3p[nt][2]);
            }
        }
    }

    #pragma unroll
    for (int nt = 0; nt < 4; nt++) {
        #pragma unroll
        for (int j = 0; j < 3; j++) {
            float v = X3p[nt][j];
            v += __shfl_xor(v, 16, 64);
            v += __shfl_xor(v, 32, 64);
            X3p[nt][j] = v;
        }
    }
    if (quad == 0) {
        #pragma unroll
        for (int nt = 0; nt < 4; nt++) {
            const int col = colBase + nt*16 + m;
            sX3[col*3 + 0] = X3p[nt][0];
            sX3[col*3 + 1] = X3p[nt][1];
            sX3[col*3 + 2] = X3p[nt][2];
        }
    }
    __syncthreads();

    if (tid < 64) {
        const int sGlob = blockIdx.x * 64 + tid;
        float X3v[3][5];
        #pragma unroll
        for (int t = 0; t < 5; t++)
            #pragma unroll
            for (int j = 0; j < 3; j++)
                X3v[j][t] = sX3[(tid*5 + t)*3 + j];

        const float lam  = sC[33];
        const float olam = 1.f - lam;
        float y[3];
        #pragma unroll
        for (int j = 0; j < 3; j++) {
            float S[5];
            #pragma unroll
            for (int t = 0; t < 5; t++) {
                float a = 0.f;
                #pragma unroll
                for (int k = 0; k < 5; k++)
                    a = fmaf(X3v[j][k], sC[k*5 + t], a);
                S[t] = a;
            }
            float mx = S[0];
            #pragma unroll
            for (int t = 1; t < 5; t++) mx = fmaxf(mx, S[t]);
            float ex[5], se = 0.f;
            #pragma unroll
            for (int t = 0; t < 5; t++) { ex[t] = __expf(S[t] - mx); se += ex[t]; }
            const float inv = 1.f / se;
            float yj = sC[30 + j];
            #pragma unroll
            for (int t = 0; t < 5; t++) {
                const float a  = ex[t] * inv;
                const float xc = X3v[j][t] * (lam + olam * a);
                yj = fmaf(xc, sC[25 + t], yj);
            }
            y[j] = yj;
        }
        const float mx = fmaxf(y[0], fmaxf(y[1], y[2]));
        const float e0 = __expf(y[0]-mx), e1 = __expf(y[1]-mx), e2 = __expf(y[2]-mx);
        const float inv = 1.f / (e0 + e1 + e2);
        if (sGlob < nsamp) {
            float* o = out + (size_t)sGlob*3;
            o[0] = e0*inv; o[1] = e1*inv; o[2] = e2*inv;
        }
    }
}

extern "C" void kernel_launch(void* const* d_in, const int* in_sizes, int n_in,
                              void* d_out, int out_size, void* d_ws, size_t ws_size,
                              hipStream_t stream) {
    const float* x   = (const float*)d_in[0];
    const float* W1  = (const float*)d_in[1];
    const float* W2  = (const float*)d_in[2];
    const float* B   = (const float*)d_in[3];
    const float* Tw1 = (const float*)d_in[4];
    const float* Tw  = (const float*)d_in[5];
    const float* Tw2 = (const float*)d_in[6];
    const float* TB  = (const float*)d_in[7];
    const float* l   = (const float*)d_in[8];
    float* out = (float*)d_out;
    float* ws  = (float*)d_ws;

    hipLaunchKernelGGL(prep_kernel, dim3(1), dim3(NTP), 0, stream,
                       W1, W2, B, Tw1, Tw, Tw2, TB, l, ws);

    const int nsamp  = in_sizes[0] / 400;
    const int ngrp   = (nsamp + 63) / 64;
    const size_t zoff   = 16384;                       // bytes; 16 KB aligned
    const size_t zbytes = (size_t)ngrp * 12800 * 2;    // [ngrp][320][40] bf16

    if (ws_size >= zoff + zbytes) {
        unsigned short* zg = (unsigned short*)((char*)ws + zoff);
        const int zblocks = (nsamp * 20 + 255) / 256;
        hipLaunchKernelGGL(zgemm_kernel, dim3(zblocks), dim3(256), 0, stream,
                           x, ws, zg, nsamp);
        hipLaunchKernelGGL(btabl_gemm, dim3(ngrp), dim3(NTM), 0, stream,
                           zg, ws, out, nsamp);
    } else {
        hipLaunchKernelGGL(btabl_main, dim3(ngrp), dim3(NTM), 0, stream,
                           x, ws, out, nsamp);
    }
}

// Round 4
// 345.938 us; speedup vs baseline: 1.0707x; 1.0707x over previous
//
#include <hip/hip_runtime.h>
#include <stdint.h>

// m_btabl — round 7: barrier-free wave-independent monolith.
//
// r6 post-mortem: two-kernel split REGRESSED (+36 us) — Z round-trip +
// extra dependent launch + lost overlap cost more than clean regimes
// bought. Reverted. The monolith's residual (~113 us vs ~30 us floor) is
// the block-wide barrier convoy: all 5 waves lock-step through
// stream->barrier->GEMM->barrier->tail (r3 occupancy 14.4% ~= 1 block/CU
// effective despite 3-block LDS capacity).
//
// r7: wave w owns samples 16w..16w+15 END-TO-END:
//   * stage-1: wave streams its own 16 samples (5 rounds x 64 lanes of
//     80 B row-pair jobs), writes its own 80 sZ cols. Wave-local RAW on
//     sZ is ordered by compiler lgkmcnt — no barrier.
//   * stage-2: wave's 5 n-tiles (cols 80w..80w+79). The k=40..47 one-hot
//     augmentation is SYNTHESIZED in the quad-1 B-fragment (bf16 1.0 at
//     element (nt+m)%5) -> sZ rows shrink 48 -> 40 ushorts.
//   * X3 quad-reduce via shfl_xor (intra-wave); sX3 aliases the wave's
//     own dead sZ slice (Bf already in regs).
//   * stage-3 tail on 48 lanes of the same wave ((sample,j) per lane,
//     final 3-way softmax via __shfl).
// ONE __syncthreads total, right after symmetric weight staging.
// LDS = 40,240 B -> 4 blocks/CU = 16 independent wave-pipelines;
// __launch_bounds__(256,4) caps VGPR at 128 so they fit.
//
// ws layout (floats) from prep_kernel (unchanged):
//   [0,3096)     W1 image, bf16 ushort[129*48] (bias folded at k=40..44, row128=0)
//   [3096,3608)  w1b pack f32 [128][4]
//   [3608,3644)  consts: Wm(25, diag 0.2) | W2b(5) | TB(3) | lam | pad
//   [3644,3694)  W2s (50)

typedef short bf16x8 __attribute__((ext_vector_type(8)));
typedef float f32x4v __attribute__((ext_vector_type(4)));

#define NTP 256
#define NTM 256

__device__ __forceinline__ unsigned short f2bf(float f) {
    unsigned int u = __float_as_uint(f);
    u += 0x7FFFu + ((u >> 16) & 1u);   // round-to-nearest-even
    return (unsigned short)(u >> 16);
}

// ---------------- prep kernel (unchanged) ----------------
__device__ __forceinline__ float block_reduce_sum(float v, float* red, int tid) {
    #pragma unroll
    for (int off = 32; off > 0; off >>= 1) v += __shfl_xor(v, off, 64);
    if ((tid & 63) == 0) red[tid >> 6] = v;
    __syncthreads();
    float r = red[0] + red[1] + red[2] + red[3];
    __syncthreads();
    return r;
}

__global__ __launch_bounds__(NTP)
void prep_kernel(const float* __restrict__ W1, const float* __restrict__ W2,
                 const float* __restrict__ B,  const float* __restrict__ Tw1,
                 const float* __restrict__ Tw, const float* __restrict__ Tw2,
                 const float* __restrict__ TB, const float* __restrict__ l,
                 float* __restrict__ ws)
{
    __shared__ float red[4];
    const int tid = threadIdx.x;
    float ss;
    ss = 0.f; for (int i = tid; i < 4800; i += NTP) { float w = W1[i];  ss += w*w; }
    const float n1 = sqrtf(block_reduce_sum(ss, red, tid));
    ss = 0.f; for (int i = tid; i < 50;   i += NTP) { float w = W2[i];  ss += w*w; }
    const float n2 = sqrtf(block_reduce_sum(ss, red, tid));
    ss = 0.f; for (int i = tid; i < 360;  i += NTP) { float w = Tw1[i]; ss += w*w; }
    const float n3 = sqrtf(block_reduce_sum(ss, red, tid));
    ss = 0.f; for (int i = tid; i < 25;   i += NTP) { float w = Tw[i];  ss += w*w; }
    const float n4 = sqrtf(block_reduce_sum(ss, red, tid));
    ss = 0.f; for (int i = tid; i < 5;    i += NTP) { float w = Tw2[i]; ss += w*w; }
    const float n5 = sqrtf(block_reduce_sum(ss, red, tid));

    const float s1 = n1 > 10.f ? 10.f/(1e-8f+n1) : 1.f;
    const float s2 = n2 > 10.f ? 10.f/(1e-8f+n2) : 1.f;
    const float s3 = n3 > 10.f ? 10.f/(1e-8f+n3) : 1.f;
    const float s4 = n4 > 10.f ? 10.f/(1e-8f+n4) : 1.f;
    const float s5 = n5 > 10.f ? 10.f/(1e-8f+n5) : 1.f;

    unsigned short* img = (unsigned short*)ws;
    for (int i = tid; i < 129*48; i += NTP) {
        const int e = i / 48, k = i - e*48;
        float v = 0.f;
        if (e < 120) {
            if (k < 40)      v = W1[e*40 + k] * s1;
            else if (k < 45) v = B[e*5 + (k-40)];
        }
        img[i] = f2bf(v);
    }
    for (int i = tid; i < 512; i += NTP) {
        const int e = i >> 2, c = i & 3;
        ws[3096 + i] = (c < 3 && e < 120) ? Tw1[c*120 + e] * s3 : 0.f;
    }
    for (int i = tid; i < 36; i += NTP) {
        float v = 0.f;
        if (i < 25)      { int r = i/5, c = i - r*5; v = (r == c) ? 0.2f : Tw[i]*s4; }
        else if (i < 30) v = Tw2[i-25] * s5;
        else if (i < 33) v = TB[i-30];
        else if (i == 33){ float lv = l[0]; v = fminf(fmaxf(lv, 0.f), 1.f); }
        ws[3608 + i] = v;
    }
    for (int i = tid; i < 50; i += NTP) ws[3644 + i] = W2[i] * s2;
}

// ---------------- main kernel ----------------
__global__ __launch_bounds__(NTM, 4)
void btabl_main(const float* __restrict__ x, const float* __restrict__ ws,
                float* __restrict__ out, int nsamp)
{
    __align__(16) __shared__ unsigned short sW1[129*48];       // 12384 B
    __align__(16) __shared__ float          sWp[128*4];        // 2048 B
    __align__(16) __shared__ float          sC[36];            // 144 B
    __align__(16) __shared__ unsigned short sZ[320*40 + 32];   // 25664 B
    // total 40,240 B -> 4 blocks/CU

    const int tid  = threadIdx.x;
    const int wave = tid >> 6;
    const int lane = tid & 63;

    // ---- stage weights into LDS (only block-wide phase) ----
    {
        const float4* src = (const float4*)ws;
        float4* d1 = (float4*)sW1;
        #pragma unroll
        for (int i = 0; i < 4; i++) {
            const int idx = tid + i*NTM;
            if (idx < 774) d1[idx] = src[idx];
        }
        if (tid < 128) ((float4*)sWp)[tid] = src[774 + tid];
        if (tid < 9)   ((float4*)sC)[tid]  = src[902 + tid];
    }
    __syncthreads();   // the ONLY barrier: symmetric ~15 KB staging

    // ---- stage 1: wave-local x stream -> Z (bf16) -> own sZ cols ----
    // wave w owns samples 16w..16w+15; job = (round,lane): sl = job/20,
    // r20 = job%20 -> rows 2*r20, 2*r20+1 (80 B, 16B-aligned).
    {
        const float* W2p = ws + 3644;                          // uniform -> s_load
        #pragma unroll
        for (int r = 0; r < 5; r++) {
            const int job = r*64 + lane;
            const int sl  = job / 20;
            const int r20 = job - sl*20;
            int sG = blockIdx.x*64 + wave*16 + sl;
            sG = sG < nsamp ? sG : (nsamp - 1);                // tail-safe
            const float4* xv = (const float4*)(x + (size_t)sG*400 + r20*20);
            float xf[20];
            #pragma unroll
            for (int i = 0; i < 5; i++) {
                const float4 q = xv[i];                        // global_load_dwordx4
                xf[i*4+0] = q.x; xf[i*4+1] = q.y; xf[i*4+2] = q.z; xf[i*4+3] = q.w;
            }
            const int col0 = (wave*16 + sl)*5;
            #pragma unroll
            for (int t = 0; t < 5; t++) {
                float z0 = 0.f, z1 = 0.f;
                #pragma unroll
                for (int k = 0; k < 10; k++) {
                    const float w = W2p[k*5 + t];              // SGPR operand
                    z0 = fmaf(xf[k],      w, z0);
                    z1 = fmaf(xf[10 + k], w, z1);
                }
                *(unsigned int*)(sZ + (col0 + t)*40 + 2*r20) =
                    (unsigned int)f2bf(z0) | ((unsigned int)f2bf(z1) << 16);
            }
        }
    }
    // no barrier: sZ RAW below is same-wave, ordered by lgkmcnt.

    // ---- stage 2: MFMA GEMM over own 5 n-tiles + X3 epilogue ----
    const int quad = lane >> 4;
    const int m    = lane & 15;
    const int colBase = wave * 80;

    bf16x8 Bf0[5], Bf1[5];
    const bf16x8 z8 = {0,0,0,0,0,0,0,0};
    #pragma unroll
    for (int nt = 0; nt < 5; nt++) {
        const int col = colBase + nt*16 + m;
        Bf0[nt] = *(const bf16x8*)(sZ + col*40 + quad*8);      // k = 8*quad..+7
        // k=32..47 half: quad0 reads k32..39; quad1 = synthesized one-hot
        // (bias aug, bf16 1.0 at element col%5 = (nt+m)%5); quads 2,3 = 0.
        const bf16x8 braw = *(const bf16x8*)(sZ + col*40 + (quad == 0 ? 32 : 0));
        bf16x8 v = z8;
        if (quad == 0) v = braw;
        if (quad == 1) {
            const int oh = (nt + m) % 5;
            #pragma unroll
            for (int j = 0; j < 5; j++) v[j] = (oh == j) ? (short)0x3F80 : (short)0;
        }
        Bf1[nt] = v;
    }

    float X3p[5][3];
    #pragma unroll
    for (int nt = 0; nt < 5; nt++)
        #pragma unroll
        for (int j = 0; j < 3; j++) X3p[nt][j] = 0.f;

    const f32x4v zacc = {0.f, 0.f, 0.f, 0.f};
    #pragma unroll
    for (int mt = 0; mt < 8; mt++) {
        const unsigned short* arow = sW1 + (mt*16 + m)*48;
        const bf16x8 A0 = *(const bf16x8*)(arow + quad*8);
        const bf16x8 A1 = *(const bf16x8*)(arow + 32 + quad*8);   // q2/3 cross rows: x0 anyway
        f32x4v wp[4];
        #pragma unroll
        for (int r = 0; r < 4; r++)
            wp[r] = *(const f32x4v*)(sWp + (mt*16 + quad*4 + r)*4);
        #pragma unroll
        for (int nt = 0; nt < 5; nt++) {
            f32x4v acc = __builtin_amdgcn_mfma_f32_16x16x32_bf16(A0, Bf0[nt], zacc, 0, 0, 0);
            acc = __builtin_amdgcn_mfma_f32_16x16x32_bf16(A1, Bf1[nt], acc, 0, 0, 0);
            #pragma unroll
            for (int r = 0; r < 4; r++) {
                const float h = fmaxf(acc[r], 0.f);               // bias folded in GEMM
                X3p[nt][0] = fmaf(wp[r][0], h, X3p[nt][0]);
                X3p[nt][1] = fmaf(wp[r][1], h, X3p[nt][1]);
                X3p[nt][2] = fmaf(wp[r][2], h, X3p[nt][2]);
            }
        }
    }

    // quad-reduce X3 partials (intra-wave), park in own dead sZ slice
    #pragma unroll
    for (int nt = 0; nt < 5; nt++) {
        #pragma unroll
        for (int j = 0; j < 3; j++) {
            float v = X3p[nt][j];
            v += __shfl_xor(v, 16, 64);
            v += __shfl_xor(v, 32, 64);
            X3p[nt][j] = v;
        }
    }
    float* sX3w = (float*)(sZ + wave*3200);    // byte 6400*wave: own slice, Bf consumed
    if (quad == 0) {
        #pragma unroll
        for (int nt = 0; nt < 5; nt++) {
            const int cLoc = nt*16 + m;        // wave-local col 0..79
            sX3w[cLoc*3 + 0] = X3p[nt][0];
            sX3w[cLoc*3 + 1] = X3p[nt][1];
            sX3w[cLoc*3 + 2] = X3p[nt][2];
        }
    }
    // no barrier: same-wave LDS write->read ordered by lgkmcnt.

    // ---- stage 3: tail on 48 lanes of the same wave: lane = (s,j) ----
    {
        const int sdiv = lane / 3;
        const int j    = lane - sdiv*3;
        const int sLoc = sdiv & 15;            // lanes >= 48 fold (results unused)
        float X3v[5];
        #pragma unroll
        for (int t = 0; t < 5; t++) X3v[t] = sX3w[(sLoc*5 + t)*3 + j];

        const float lam  = sC[33];
        const float olam = 1.f - lam;
        float S[5];
        #pragma unroll
        for (int t = 0; t < 5; t++) {
            float a = 0.f;
            #pragma unroll
            for (int k = 0; k < 5; k++) a = fmaf(X3v[k], sC[k*5 + t], a);
            S[t] = a;
        }
        float mx = S[0];
        #pragma unroll
        for (int t = 1; t < 5; t++) mx = fmaxf(mx, S[t]);
        float ex[5], se = 0.f;
        #pragma unroll
        for (int t = 0; t < 5; t++) { ex[t] = __expf(S[t] - mx); se += ex[t]; }
        const float inv = 1.f / se;
        float yj = sC[30 + j];
        #pragma unroll
        for (int t = 0; t < 5; t++) {
            const float a  = ex[t] * inv;
            const float xc = X3v[t] * (lam + olam * a);
            yj = fmaf(xc, sC[25 + t], yj);
        }
        // gather this sample's 3 components (all lanes execute the shfl)
        const float ya = __shfl(yj, sLoc*3 + 0, 64);
        const float yb = __shfl(yj, sLoc*3 + 1, 64);
        const float yc = __shfl(yj, sLoc*3 + 2, 64);
        const float my = fmaxf(ya, fmaxf(yb, yc));
        const float sse = __expf(ya - my) + __expf(yb - my) + __expf(yc - my);
        const float p = __expf(yj - my) / sse;
        const int sG = blockIdx.x*64 + wave*16 + sLoc;
        if (lane < 48 && sG < nsamp) out[(size_t)sG*3 + j] = p;
    }
}

extern "C" void kernel_launch(void* const* d_in, const int* in_sizes, int n_in,
                              void* d_out, int out_size, void* d_ws, size_t ws_size,
                              hipStream_t stream) {
    const float* x   = (const float*)d_in[0];
    const float* W1  = (const float*)d_in[1];
    const float* W2  = (const float*)d_in[2];
    const float* B   = (const float*)d_in[3];
    const float* Tw1 = (const float*)d_in[4];
    const float* Tw  = (const float*)d_in[5];
    const float* Tw2 = (const float*)d_in[6];
    const float* TB  = (const float*)d_in[7];
    const float* l   = (const float*)d_in[8];
    float* out = (float*)d_out;
    float* ws  = (float*)d_ws;

    hipLaunchKernelGGL(prep_kernel, dim3(1), dim3(NTP), 0, stream,
                       W1, W2, B, Tw1, Tw, Tw2, TB, l, ws);

    const int nsamp = in_sizes[0] / 400;
    const int grid  = (nsamp + 63) / 64;
    hipLaunchKernelGGL(btabl_main, dim3(grid), dim3(NTM), 0, stream,
                       x, ws, out, nsamp);
}

// Round 8
// 330.664 us; speedup vs baseline: 1.1202x; 1.0462x over previous
//
#include <hip/hip_runtime.h>
#include <stdint.h>

// m_btabl — round 11: identical resubmission of r9/r10 (rounds 8-10 all
// died to "MI355X container failed twice" — a container-ACQUISITION
// failure that occurs before kernel compile/execution; kernel content
// cannot cause it. Device-side audit x2: all LDS/global accesses
// statically in-bounds, one uniform barrier, no data-dependent loops.
// Harness timings in successful rounds already showed infra degradation:
// push_in_npz_s 740s/3328s/1608s).
//
// r7 post-mortem (live theory): WRITE_SIZE 36.8 MB vs 1.5 MB of actual
// output = ~35 MB of scratch spill traffic. VGPR_Count 64 with stage-2
// holding Bf0[5]+Bf1[5]+X3p[5][3]+wp[4] => allocator spilled the fragment
// arrays under __launch_bounds__(256,4); scratch ops in the MFMA loop
// serialize each wave at HBM-class latency (VALU 19%, Mfma 3.4%, HBM 16%
// — all idle). Occupancy DID go 14% -> 41% as designed.
//
// Fix: stage-2 loop nest inverted — outer nt (5), inner mt (8):
//   per nt: one Bf0 + one Bf1 (8 regs), 3 scalar X3 partials,
//   quad-reduce + per-nt store into the wave's sX3 slice. A0/A1/wp are
//   re-read from LDS each nt (5x redundant LDS reads — free at ~2% LDS
//   util). Register peak drops ~40 regs; no spills expected.
//   WAR safety: per-nt X3 writes land in bytes [nt*192, nt*192+192) of
//   the wave slice (max 960); Bf reads for nt' > nt start at byte
//   nt'*1280 >= 1280 — never overlapping; same-wave LDS is in-order.
// __launch_bounds__(256,3): ~170 VGPR headroom guarantees no spills
// (LDS already caps at 4 blocks/CU; spills cost more than occupancy).
// Everything else (barrier-free wave-independent structure, stage-1
// stream, 48-lane tail) unchanged from r7.
//
// ws layout (floats) from prep_kernel (unchanged):
//   [0,3096)     W1 image, bf16 ushort[129*48] (bias folded at k=40..44, row128=0)
//   [3096,3608)  w1b pack f32 [128][4]
//   [3608,3644)  consts: Wm(25, diag 0.2) | W2b(5) | TB(3) | lam | pad
//   [3644,3694)  W2s (50)

typedef short bf16x8 __attribute__((ext_vector_type(8)));
typedef float f32x4v __attribute__((ext_vector_type(4)));

#define NTP 256
#define NTM 256

__device__ __forceinline__ unsigned short f2bf(float f) {
    unsigned int u = __float_as_uint(f);
    u += 0x7FFFu + ((u >> 16) & 1u);   // round-to-nearest-even
    return (unsigned short)(u >> 16);
}

// ---------------- prep kernel (unchanged) ----------------
__device__ __forceinline__ float block_reduce_sum(float v, float* red, int tid) {
    #pragma unroll
    for (int off = 32; off > 0; off >>= 1) v += __shfl_xor(v, off, 64);
    if ((tid & 63) == 0) red[tid >> 6] = v;
    __syncthreads();
    float r = red[0] + red[1] + red[2] + red[3];
    __syncthreads();
    return r;
}

__global__ __launch_bounds__(NTP)
void prep_kernel(const float* __restrict__ W1, const float* __restrict__ W2,
                 const float* __restrict__ B,  const float* __restrict__ Tw1,
                 const float* __restrict__ Tw, const float* __restrict__ Tw2,
                 const float* __restrict__ TB, const float* __restrict__ l,
                 float* __restrict__ ws)
{
    __shared__ float red[4];
    const int tid = threadIdx.x;
    float ss;
    ss = 0.f; for (int i = tid; i < 4800; i += NTP) { float w = W1[i];  ss += w*w; }
    const float n1 = sqrtf(block_reduce_sum(ss, red, tid));
    ss = 0.f; for (int i = tid; i < 50;   i += NTP) { float w = W2[i];  ss += w*w; }
    const float n2 = sqrtf(block_reduce_sum(ss, red, tid));
    ss = 0.f; for (int i = tid; i < 360;  i += NTP) { float w = Tw1[i]; ss += w*w; }
    const float n3 = sqrtf(block_reduce_sum(ss, red, tid));
    ss = 0.f; for (int i = tid; i < 25;   i += NTP) { float w = Tw[i];  ss += w*w; }
    const float n4 = sqrtf(block_reduce_sum(ss, red, tid));
    ss = 0.f; for (int i = tid; i < 5;    i += NTP) { float w = Tw2[i]; ss += w*w; }
    const float n5 = sqrtf(block_reduce_sum(ss, red, tid));

    const float s1 = n1 > 10.f ? 10.f/(1e-8f+n1) : 1.f;
    const float s2 = n2 > 10.f ? 10.f/(1e-8f+n2) : 1.f;
    const float s3 = n3 > 10.f ? 10.f/(1e-8f+n3) : 1.f;
    const float s4 = n4 > 10.f ? 10.f/(1e-8f+n4) : 1.f;
    const float s5 = n5 > 10.f ? 10.f/(1e-8f+n5) : 1.f;

    unsigned short* img = (unsigned short*)ws;
    for (int i = tid; i < 129*48; i += NTP) {
        const int e = i / 48, k = i - e*48;
        float v = 0.f;
        if (e < 120) {
            if (k < 40)      v = W1[e*40 + k] * s1;
            else if (k < 45) v = B[e*5 + (k-40)];
        }
        img[i] = f2bf(v);
    }
    for (int i = tid; i < 512; i += NTP) {
        const int e = i >> 2, c = i & 3;
        ws[3096 + i] = (c < 3 && e < 120) ? Tw1[c*120 + e] * s3 : 0.f;
    }
    for (int i = tid; i < 36; i += NTP) {
        float v = 0.f;
        if (i < 25)      { int r = i/5, c = i - r*5; v = (r == c) ? 0.2f : Tw[i]*s4; }
        else if (i < 30) v = Tw2[i-25] * s5;
        else if (i < 33) v = TB[i-30];
        else if (i == 33){ float lv = l[0]; v = fminf(fmaxf(lv, 0.f), 1.f); }
        ws[3608 + i] = v;
    }
    for (int i = tid; i < 50; i += NTP) ws[3644 + i] = W2[i] * s2;
}

// ---------------- main kernel ----------------
__global__ __launch_bounds__(NTM, 3)
void btabl_main(const float* __restrict__ x, const float* __restrict__ ws,
                float* __restrict__ out, int nsamp)
{
    __align__(16) __shared__ unsigned short sW1[129*48];       // 12384 B
    __align__(16) __shared__ float          sWp[128*4];        // 2048 B
    __align__(16) __shared__ float          sC[36];            // 144 B
    __align__(16) __shared__ unsigned short sZ[320*40 + 32];   // 25664 B
    // total 40,240 B -> 4 blocks/CU (LDS-bound)

    const int tid  = threadIdx.x;
    const int wave = tid >> 6;
    const int lane = tid & 63;

    // ---- stage weights into LDS (only block-wide phase) ----
    {
        const float4* src = (const float4*)ws;
        float4* d1 = (float4*)sW1;
        #pragma unroll
        for (int i = 0; i < 4; i++) {
            const int idx = tid + i*NTM;
            if (idx < 774) d1[idx] = src[idx];
        }
        if (tid < 128) ((float4*)sWp)[tid] = src[774 + tid];
        if (tid < 9)   ((float4*)sC)[tid]  = src[902 + tid];
    }
    __syncthreads();   // the ONLY barrier: symmetric ~15 KB staging

    // ---- stage 1: wave-local x stream -> Z (bf16) -> own sZ cols ----
    // wave w owns samples 16w..16w+15; job = (round,lane): sl = job/20,
    // r20 = job%20 -> rows 2*r20, 2*r20+1 (80 B, 16B-aligned).
    {
        const float* W2p = ws + 3644;                          // uniform -> s_load
        #pragma unroll
        for (int r = 0; r < 5; r++) {
            const int job = r*64 + lane;
            const int sl  = job / 20;
            const int r20 = job - sl*20;
            int sG = blockIdx.x*64 + wave*16 + sl;
            sG = sG < nsamp ? sG : (nsamp - 1);                // tail-safe
            const float4* xv = (const float4*)(x + (size_t)sG*400 + r20*20);
            float xf[20];
            #pragma unroll
            for (int i = 0; i < 5; i++) {
                const float4 q = xv[i];                        // global_load_dwordx4
                xf[i*4+0] = q.x; xf[i*4+1] = q.y; xf[i*4+2] = q.z; xf[i*4+3] = q.w;
            }
            const int col0 = (wave*16 + sl)*5;
            #pragma unroll
            for (int t = 0; t < 5; t++) {
                float z0 = 0.f, z1 = 0.f;
                #pragma unroll
                for (int k = 0; k < 10; k++) {
                    const float w = W2p[k*5 + t];              // SGPR operand
                    z0 = fmaf(xf[k],      w, z0);
                    z1 = fmaf(xf[10 + k], w, z1);
                }
                *(unsigned int*)(sZ + (col0 + t)*40 + 2*r20) =
                    (unsigned int)f2bf(z0) | ((unsigned int)f2bf(z1) << 16);
            }
        }
    }
    // no barrier: sZ RAW below is same-wave, ordered by lgkmcnt.

    // ---- stage 2: MFMA GEMM, outer nt / inner mt (low register pressure) ----
    const int quad = lane >> 4;
    const int m    = lane & 15;
    const int colBase = wave * 80;
    float* sX3w = (float*)(sZ + wave*3200);    // wave's own slice (bytes 6400w..)

    const f32x4v zacc = {0.f, 0.f, 0.f, 0.f};
    const bf16x8 z8 = {0,0,0,0,0,0,0,0};
    #pragma unroll
    for (int nt = 0; nt < 5; nt++) {
        const int col = colBase + nt*16 + m;
        const bf16x8 Bf0 = *(const bf16x8*)(sZ + col*40 + quad*8);   // k=8q..8q+7
        // k=32..47 half: quad0 reads k32..39; quad1 = synthesized one-hot
        // (bias aug, bf16 1.0 at element col%5 = (nt+m)%5); quads 2,3 = 0.
        bf16x8 Bf1 = z8;
        if (quad == 0) Bf1 = *(const bf16x8*)(sZ + col*40 + 32);
        else if (quad == 1) {
            const int oh = (nt + m) % 5;
            #pragma unroll
            for (int j = 0; j < 5; j++) Bf1[j] = (oh == j) ? (short)0x3F80 : (short)0;
        }

        float p0 = 0.f, p1 = 0.f, p2 = 0.f;
        #pragma unroll
        for (int mt = 0; mt < 8; mt++) {
            const unsigned short* arow = sW1 + (mt*16 + m)*48;
            const bf16x8 A0 = *(const bf16x8*)(arow + quad*8);
            const bf16x8 A1 = *(const bf16x8*)(arow + 32 + quad*8);  // q2/3 cross rows: x0 anyway
            f32x4v acc = __builtin_amdgcn_mfma_f32_16x16x32_bf16(A0, Bf0, zacc, 0, 0, 0);
            acc = __builtin_amdgcn_mfma_f32_16x16x32_bf16(A1, Bf1, acc, 0, 0, 0);
            #pragma unroll
            for (int r = 0; r < 4; r++) {
                const float h = fmaxf(acc[r], 0.f);                  // bias folded in GEMM
                const f32x4v wp = *(const f32x4v*)(sWp + (mt*16 + quad*4 + r)*4);
                p0 = fmaf(wp[0], h, p0);
                p1 = fmaf(wp[1], h, p1);
                p2 = fmaf(wp[2], h, p2);
            }
        }

        // quad-reduce (intra-wave) + per-nt store into own sX3 slice.
        p0 += __shfl_xor(p0, 16, 64); p0 += __shfl_xor(p0, 32, 64);
        p1 += __shfl_xor(p1, 16, 64); p1 += __shfl_xor(p1, 32, 64);
        p2 += __shfl_xor(p2, 16, 64); p2 += __shfl_xor(p2, 32, 64);
        if (quad == 0) {
            const int cLoc = nt*16 + m;        // wave-local col 0..79
            sX3w[cLoc*3 + 0] = p0;
            sX3w[cLoc*3 + 1] = p1;
            sX3w[cLoc*3 + 2] = p2;
        }
    }
    // no barrier: same-wave LDS write->read ordered by lgkmcnt.

    // ---- stage 3: tail on 48 lanes of the same wave: lane = (s,j) ----
    {
        const int sdiv = lane / 3;
        const int j    = lane - sdiv*3;
        const int sLoc = sdiv & 15;            // lanes >= 48 fold (results unused)
        float X3v[5];
        #pragma unroll
        for (int t = 0; t < 5; t++) X3v[t] = sX3w[(sLoc*5 + t)*3 + j];

        const float lam  = sC[33];
        const float olam = 1.f - lam;
        float S[5];
        #pragma unroll
        for (int t = 0; t < 5; t++) {
            float a = 0.f;
            #pragma unroll
            for (int k = 0; k < 5; k++) a = fmaf(X3v[k], sC[k*5 + t], a);
            S[t] = a;
        }
        float mx = S[0];
        #pragma unroll
        for (int t = 1; t < 5; t++) mx = fmaxf(mx, S[t]);
        float ex[5], se = 0.f;
        #pragma unroll
        for (int t = 0; t < 5; t++) { ex[t] = __expf(S[t] - mx); se += ex[t]; }
        const float inv = 1.f / se;
        float yj = sC[30 + j];
        #pragma unroll
        for (int t = 0; t < 5; t++) {
            const float a  = ex[t] * inv;
            const float xc = X3v[t] * (lam + olam * a);
            yj = fmaf(xc, sC[25 + t], yj);
        }
        // gather this sample's 3 components (all lanes execute the shfl)
        const float ya = __shfl(yj, sLoc*3 + 0, 64);
        const float yb = __shfl(yj, sLoc*3 + 1, 64);
        const float yc = __shfl(yj, sLoc*3 + 2, 64);
        const float my = fmaxf(ya, fmaxf(yb, yc));
        const float sse = __expf(ya - my) + __expf(yb - my) + __expf(yc - my);
        const float p = __expf(yj - my) / sse;
        const int sG = blockIdx.x*64 + wave*16 + sLoc;
        if (lane < 48 && sG < nsamp) out[(size_t)sG*3 + j] = p;
    }
}

extern "C" void kernel_launch(void* const* d_in, const int* in_sizes, int n_in,
                              void* d_out, int out_size, void* d_ws, size_t ws_size,
                              hipStream_t stream) {
    const float* x   = (const float*)d_in[0];
    const float* W1  = (const float*)d_in[1];
    const float* W2  = (const float*)d_in[2];
    const float* B   = (const float*)d_in[3];
    const float* Tw1 = (const float*)d_in[4];
    const float* Tw  = (const float*)d_in[5];
    const float* Tw2 = (const float*)d_in[6];
    const float* TB  = (const float*)d_in[7];
    const float* l   = (const float*)d_in[8];
    float* out = (float*)d_out;
    float* ws  = (float*)d_ws;

    hipLaunchKernelGGL(prep_kernel, dim3(1), dim3(NTP), 0, stream,
                       W1, W2, B, Tw1, Tw, Tw2, TB, l, ws);

    const int nsamp = in_sizes[0] / 400;
    const int grid  = (nsamp + 63) / 64;
    hipLaunchKernelGGL(btabl_main, dim3(grid), dim3(NTM), 0, stream,
                       x, ws, out, nsamp);
}